// Round 5
// baseline (1337.143 us; speedup 1.0000x reference)
//
#include <hip/hip_runtime.h>
#include <hip/hip_bf16.h>

#define NMESH 50000
#define GRIDN 32768
#define NEDGE 131072
#define HID 384
#define CHUNK 32768
#define NCHUNK 4

using f32x4 = __attribute__((ext_vector_type(4))) float;
using bfrag = __attribute__((ext_vector_type(8))) short;
using i32x4 = __attribute__((ext_vector_type(4))) int;

__device__ __forceinline__ float gelu_f(float v) {
    return 0.5f * v * (1.0f + erff(v * 0.70710678118654752f));
}

// bijective XCD-chunking swizzle (m204)
__device__ __forceinline__ void xcd_swizzle(int& bx, int& by) {
    int gx = gridDim.x;
    int nwg = gx * gridDim.y;
    int l = blockIdx.y * gx + blockIdx.x;
    int q = nwg >> 3, r = nwg & 7;
    int xcd = l & 7, pos = l >> 3;
    int nl = (xcd < r ? xcd * (q + 1) : r * (q + 1) + (xcd - r) * q) + pos;
    by = nl / gx;
    bx = nl - by * gx;
}

// ---------------- weight transpose + bf16 cast: Wt[n*K+k] = W[k*N+n] ----------------
__global__ void transpose_to_bf16(const float* __restrict__ w, __hip_bfloat16* __restrict__ wt,
                                  int K, int N) {
    int idx = blockIdx.x * blockDim.x + threadIdx.x;
    if (idx >= K * N) return;
    int n = idx / K;
    int k = idx - n * K;
    wt[idx] = __float2bfloat16(w[(size_t)k * N + n]);
}

// ---------------- sincos positional embedding ----------------
__global__ void embed_kernel(const float* __restrict__ pos, __hip_bfloat16* __restrict__ outp,
                             int n, int stride, int coloff) {
    int idx = blockIdx.x * blockDim.x + threadIdx.x;
    if (idx >= n * 96) return;
    int nn = idx / 96;
    int rr = idx - nn * 96;
    int d = rr >> 5;
    int k = rr & 31;
    float v = pos[nn * 3 + d];
    float omega = expf(-0.28782313662425575f * (float)k);  // ln(10000)/32
    float a = v * omega;
    __hip_bfloat16* o = outp + (size_t)nn * stride + coloff + d * 64 + k;
    o[0]  = __float2bfloat16(sinf(a));
    o[32] = __float2bfloat16(cosf(a));
}

// ---------------- layer 1: h1 = gelu(x @ w1 + b1), K=16 ----------------
__global__ void lin1_kernel(const float* __restrict__ x, const float* __restrict__ w,
                            const float* __restrict__ b, __hip_bfloat16* __restrict__ h1) {
    int idx = blockIdx.x * blockDim.x + threadIdx.x;
    if (idx >= NMESH * HID) return;
    int m = idx / HID;
    int n = idx - m * HID;
    float acc = b[n];
    const float* xr = x + m * 16;
    #pragma unroll
    for (int k = 0; k < 16; k++) acc = fmaf(xr[k], w[k * HID + n], acc);
    h1[idx] = __float2bfloat16(gelu_f(acc));
}

// ---------------- bf16 MFMA GEMM: C = act(A @ Wt^T + bias) ----------------
// 128x128 tile, BK=32, 4 waves (2x2), 16x16x32 MFMA, double-buffered LDS,
// register staging with DEPTH-2 prefetch (global->reg at step ks feeds the
// LDS write at end of step ks+1 -> ~2 MFMA phases of latency cover).
// LDS slot swizzle: slot(kc,row) = kc*128 + (row ^ (kc*2)) -> both the write
// pattern (kc=l&3,row=l>>2) and read pattern (lr consecutive) have all-8
// distinct slots mod 8 per 8-lane subgroup = conflict-free b128.
template<bool GATHER, bool GELU>
__launch_bounds__(256, 4)
__global__ void mfma_gemm(const __hip_bfloat16* __restrict__ A,
                          const __hip_bfloat16* __restrict__ Wt,
                          const float* __restrict__ bias,
                          __hip_bfloat16* __restrict__ C,
                          int M, int N, int K, int ldc,
                          const int* __restrict__ edges,
                          const __hip_bfloat16* __restrict__ meshf,
                          const __hip_bfloat16* __restrict__ gridf) {
    __shared__ __align__(16) __hip_bfloat16 As[2][4096];
    __shared__ __align__(16) __hip_bfloat16 Bs[2][4096];

    const int t = threadIdx.x;
    const int lane = t & 63;
    const int wave = t >> 6;
    const int wm0 = (wave >> 1) * 64;
    const int wn0 = (wave & 1) * 64;

    int bx, by;
    xcd_swizzle(bx, by);
    const int row0 = by * 128;
    const int col0 = bx * 128;

    // staging assignment: k-chunk kcS (0..3), rows rS0 (0..63) and rS0+64
    const int kcS = t & 3;
    const int rS0 = t >> 2;
    const int rS1 = rS0 + 64;

    const __hip_bfloat16 *aP0, *aP1, *aQ0 = nullptr, *aQ1 = nullptr;
    if constexpr (GATHER) {
        int e0 = min(row0 + rS0, M - 1);
        int e1 = min(row0 + rS1, M - 1);
        aP0 = meshf + (size_t)edges[2 * e0 + 1] * 576;
        aQ0 = gridf + (size_t)edges[2 * e0 + 0] * 192;
        aP1 = meshf + (size_t)edges[2 * e1 + 1] * 576;
        aQ1 = gridf + (size_t)edges[2 * e1 + 0] * 192;
    } else {
        aP0 = A + (size_t)min(row0 + rS0, M - 1) * K;
        aP1 = A + (size_t)min(row0 + rS1, M - 1) * K;
    }
    const __hip_bfloat16* bP0 = Wt + (size_t)(col0 + rS0) * K;
    const __hip_bfloat16* bP1 = Wt + (size_t)(col0 + rS1) * K;

    // LDS dest element offsets: slot(kc,row) = kc*128 + (row^(2kc)), *8 elems
    const int dS0 = kcS * 1024 + ((rS0 ^ (kcS << 1)) << 3);
    const int dS1 = kcS * 1024 + ((rS1 ^ (kcS << 1)) << 3);

    f32x4 acc[4][4] = {};

    const int kq = lane >> 4;
    const int lr = lane & 15;
    // fragment read base: kq*1024 + (lr^(2kq))*8 + rowbase*8 (+ i*128 per frag)
    const int rdA = kq * 1024 + ((lr ^ (kq << 1)) << 3) + wm0 * 8;
    const int rdB = kq * 1024 + ((lr ^ (kq << 1)) << 3) + wn0 * 8;

    const int nsteps = K >> 5;  // always even (12 or 24)

    struct SR { i32x4 a0, a1, b0, b1; };

    auto gload = [&](int ks, SR& s) {
        int k = ks * 32 + kcS * 8;
        if constexpr (GATHER) {
            s.a0 = *reinterpret_cast<const i32x4*>((k < 576) ? (aP0 + k) : (aQ0 + (k - 576)));
            s.a1 = *reinterpret_cast<const i32x4*>((k < 576) ? (aP1 + k) : (aQ1 + (k - 576)));
        } else {
            s.a0 = *reinterpret_cast<const i32x4*>(aP0 + k);
            s.a1 = *reinterpret_cast<const i32x4*>(aP1 + k);
        }
        s.b0 = *reinterpret_cast<const i32x4*>(bP0 + k);
        s.b1 = *reinterpret_cast<const i32x4*>(bP1 + k);
    };
    auto swrite = [&](int buf, const SR& s) {
        *reinterpret_cast<i32x4*>(&As[buf][dS0]) = s.a0;
        *reinterpret_cast<i32x4*>(&As[buf][dS1]) = s.a1;
        *reinterpret_cast<i32x4*>(&Bs[buf][dS0]) = s.b0;
        *reinterpret_cast<i32x4*>(&Bs[buf][dS1]) = s.b1;
    };
    auto compute = [&](int buf) {
        bfrag aF[4], bF[4];
        #pragma unroll
        for (int i = 0; i < 4; i++) {
            aF[i] = *reinterpret_cast<const bfrag*>(&As[buf][rdA + i * 128]);
            bF[i] = *reinterpret_cast<const bfrag*>(&Bs[buf][rdB + i * 128]);
        }
        #pragma unroll
        for (int i = 0; i < 4; i++) {
            #pragma unroll
            for (int j = 0; j < 4; j++) {
                acc[i][j] = __builtin_amdgcn_mfma_f32_16x16x32_bf16(aF[i], bF[j], acc[i][j], 0, 0, 0);
            }
        }
    };

    // prologue: step0 -> LDS buf0; step1 -> regs P1
    SR P0, P1;
    gload(0, P0);
    swrite(0, P0);
    gload(1, P1);
    __syncthreads();

    for (int ks = 0; ks < nsteps; ks += 2) {
        // phase A: compute step ks (buf0); stage step ks+1 -> buf1; load ks+2 -> P0
        if (ks + 2 < nsteps) gload(ks + 2, P0);
        compute(0);
        swrite(1, P1);
        __syncthreads();
        // phase B: compute step ks+1 (buf1); stage step ks+2 -> buf0; load ks+3 -> P1
        if (ks + 3 < nsteps) gload(ks + 3, P1);
        compute(1);
        if (ks + 2 < nsteps) swrite(0, P0);
        __syncthreads();
    }

    // C/D layout: col = lane&15, row = (lane>>4)*4 + reg
    #pragma unroll
    for (int i = 0; i < 4; i++) {
        #pragma unroll
        for (int j = 0; j < 4; j++) {
            #pragma unroll
            for (int r = 0; r < 4; r++) {
                int row = row0 + wm0 + i * 16 + kq * 4 + r;
                int col = col0 + wn0 + j * 16 + lr;
                if (row < M) {
                    float v = acc[i][j][r] + bias[col];
                    if constexpr (GELU) v = gelu_f(v);
                    C[(size_t)row * ldc + col] = __float2bfloat16(v);
                }
            }
        }
    }
}

// ---------------- per-chunk segment partial sums (sorted grid_idx, no atomics) ----------------
__global__ void seg_partial(const int* __restrict__ edges, int e0, int e1,
                            const __hip_bfloat16* __restrict__ m3c, float* __restrict__ out) {
    int g = blockIdx.x;
    int l = e0, r = e1;
    while (l < r) { int mid = (l + r) >> 1; if (edges[2 * mid] < g) l = mid + 1; else r = mid; }
    int lo = l;
    r = e1;
    while (l < r) { int mid = (l + r) >> 1; if (edges[2 * mid] <= g) l = mid + 1; else r = mid; }
    int hi = l;
    if (lo >= hi) return;

    int c = threadIdx.x;
    float s0 = 0.f, s1 = 0.f, s2 = 0.f;
    for (int e = lo; e < hi; e++) {
        const __hip_bfloat16* rp = m3c + (size_t)(e - e0) * HID;
        s0 += __bfloat162float(rp[c]);
        s1 += __bfloat162float(rp[c + 128]);
        s2 += __bfloat162float(rp[c + 256]);
    }
    float* orow = out + (size_t)g * HID;
    orow[c] += s0;
    orow[c + 128] += s1;
    orow[c + 256] += s2;
}

// ---------------- final divide by segment count ----------------
__global__ void seg_div(const int* __restrict__ edges, float* __restrict__ out) {
    int g = blockIdx.x;
    int l = 0, r = NEDGE;
    while (l < r) { int mid = (l + r) >> 1; if (edges[2 * mid] < g) l = mid + 1; else r = mid; }
    int lo = l;
    r = NEDGE;
    while (l < r) { int mid = (l + r) >> 1; if (edges[2 * mid] <= g) l = mid + 1; else r = mid; }
    int cnt = l - lo;
    float inv = 1.0f / (float)max(cnt, 1);
    int c = threadIdx.x;
    float* orow = out + (size_t)g * HID;
    orow[c] *= inv;
    orow[c + 128] *= inv;
    orow[c + 256] *= inv;
}

extern "C" void kernel_launch(void* const* d_in, const int* in_sizes, int n_in,
                              void* d_out, int out_size, void* d_ws, size_t ws_size,
                              hipStream_t stream) {
    const float* x        = (const float*)d_in[0];
    const float* mesh_pos = (const float*)d_in[1];
    const float* grid_pos = (const float*)d_in[2];
    const int*   edges    = (const int*)d_in[3];
    const float* w1  = (const float*)d_in[4];
    const float* b1  = (const float*)d_in[5];
    const float* w2  = (const float*)d_in[6];
    const float* b2  = (const float*)d_in[7];
    const float* w3  = (const float*)d_in[8];
    const float* b3  = (const float*)d_in[9];
    const float* wm1 = (const float*)d_in[10];
    const float* bm1 = (const float*)d_in[11];
    const float* wm2 = (const float*)d_in[12];
    const float* bm2 = (const float*)d_in[13];
    const float* wm3 = (const float*)d_in[14];
    const float* bm3 = (const float*)d_in[15];
    float* out = (float*)d_out;

    // ---- workspace layout, ~174 MB total ----
    char* p = (char*)d_ws;
    auto alloc = [&](size_t b) { char* r = p; p += (b + 255) & ~(size_t)255; return r; };
    __hip_bfloat16* wt2   = (__hip_bfloat16*)alloc((size_t)384 * 384 * 2);
    __hip_bfloat16* wt3   = (__hip_bfloat16*)alloc((size_t)384 * 384 * 2);
    __hip_bfloat16* wtm1  = (__hip_bfloat16*)alloc((size_t)768 * 768 * 2);
    __hip_bfloat16* wtm2  = (__hip_bfloat16*)alloc((size_t)768 * 768 * 2);
    __hip_bfloat16* wtm3  = (__hip_bfloat16*)alloc((size_t)384 * 768 * 2);
    __hip_bfloat16* gridf = (__hip_bfloat16*)alloc((size_t)GRIDN * 192 * 2);
    __hip_bfloat16* meshf = (__hip_bfloat16*)alloc((size_t)NMESH * 576 * 2);
    char* U1 = alloc((size_t)CHUNK * 768 * 2);
    char* U2 = alloc((size_t)CHUNK * 768 * 2);
    __hip_bfloat16* h1  = (__hip_bfloat16*)U1;
    __hip_bfloat16* h2  = (__hip_bfloat16*)U2;
    __hip_bfloat16* m1c = (__hip_bfloat16*)U1;
    __hip_bfloat16* m2c = (__hip_bfloat16*)U2;
    __hip_bfloat16* m3c = (__hip_bfloat16*)U1;  // m1c dead once m2c computed

    hipMemsetAsync(out, 0, (size_t)GRIDN * HID * 4, stream);

    transpose_to_bf16<<<(384 * 384 + 255) / 256, 256, 0, stream>>>(w2, wt2, 384, 384);
    transpose_to_bf16<<<(384 * 384 + 255) / 256, 256, 0, stream>>>(w3, wt3, 384, 384);
    transpose_to_bf16<<<(768 * 768 + 255) / 256, 256, 0, stream>>>(wm1, wtm1, 768, 768);
    transpose_to_bf16<<<(768 * 768 + 255) / 256, 256, 0, stream>>>(wm2, wtm2, 768, 768);
    transpose_to_bf16<<<(768 * 384 + 255) / 256, 256, 0, stream>>>(wm3, wtm3, 768, 384);

    embed_kernel<<<(NMESH * 96 + 255) / 256, 256, 0, stream>>>(mesh_pos, meshf, NMESH, 576, 384);
    embed_kernel<<<(GRIDN * 96 + 255) / 256, 256, 0, stream>>>(grid_pos, gridf, GRIDN, 192, 0);

    lin1_kernel<<<(NMESH * HID + 255) / 256, 256, 0, stream>>>(x, w1, b1, h1);

    // h2 = gelu(h1 @ w2 + b2)
    mfma_gemm<false, true><<<dim3(3, 391), 256, 0, stream>>>(
        h1, wt2, b2, h2, NMESH, 384, 384, 384, nullptr, nullptr, nullptr);
    // mesh_feat[:, :384] = h2 @ w3 + b3
    mfma_gemm<false, false><<<dim3(3, 391), 256, 0, stream>>>(
        h2, wt3, b3, meshf, NMESH, 384, 384, 576, nullptr, nullptr, nullptr);

    for (int c = 0; c < NCHUNK; c++) {
        int e0 = c * CHUNK;
        // m1c = gelu(gather(edges[e0:e0+CHUNK]) @ wm1 + bm1)
        mfma_gemm<true, true><<<dim3(6, CHUNK / 128), 256, 0, stream>>>(
            nullptr, wtm1, bm1, m1c, CHUNK, 768, 768, 768, edges + 2 * e0, meshf, gridf);
        // m2c = gelu(m1c @ wm2 + bm2)
        mfma_gemm<false, true><<<dim3(6, CHUNK / 128), 256, 0, stream>>>(
            m1c, wtm2, bm2, m2c, CHUNK, 768, 768, 768, nullptr, nullptr, nullptr);
        // m3c = m2c @ wm3 + bm3   (overwrites m1c region — m1c dead)
        mfma_gemm<false, false><<<dim3(3, CHUNK / 128), 256, 0, stream>>>(
            m2c, wtm3, bm3, m3c, CHUNK, 384, 768, 384, nullptr, nullptr, nullptr);
        // accumulate segment sums for this chunk
        seg_partial<<<GRIDN, 128, 0, stream>>>(edges, e0, e0 + CHUNK, m3c, out);
    }

    seg_div<<<GRIDN, 128, 0, stream>>>(edges, out);
}

// Round 6
// 1166.176 us; speedup vs baseline: 1.1466x; 1.1466x over previous
//
#include <hip/hip_runtime.h>
#include <hip/hip_bf16.h>

#define NMESH 50000
#define GRIDN 32768
#define NEDGE 131072
#define HID 384
#define CHUNK 32768
#define NCHUNK 4

using f32x4 = __attribute__((ext_vector_type(4))) float;
using bfrag = __attribute__((ext_vector_type(8))) short;
using i32x4 = __attribute__((ext_vector_type(4))) int;

__device__ __forceinline__ float gelu_f(float v) {
    return 0.5f * v * (1.0f + erff(v * 0.70710678118654752f));
}

__device__ __forceinline__ void load_lds16(const void* g, void* l) {
    __builtin_amdgcn_global_load_lds(
        (const __attribute__((address_space(1))) void*)g,
        (__attribute__((address_space(3))) void*)l,
        16, 0, 0);
}

// bijective XCD-chunking swizzle (m204)
__device__ __forceinline__ void xcd_swizzle(int& bx, int& by) {
    int gx = gridDim.x;
    int nwg = gx * gridDim.y;
    int l = blockIdx.y * gx + blockIdx.x;
    int q = nwg >> 3, r = nwg & 7;
    int xcd = l & 7, pos = l >> 3;
    int nl = (xcd < r ? xcd * (q + 1) : r * (q + 1) + (xcd - r) * q) + pos;
    by = nl / gx;
    bx = nl - by * gx;
}

// ---------------- weight transpose + bf16 cast: Wt[n*K+k] = W[k*N+n] ----------------
__global__ void transpose_to_bf16(const float* __restrict__ w, __hip_bfloat16* __restrict__ wt,
                                  int K, int N) {
    int idx = blockIdx.x * blockDim.x + threadIdx.x;
    if (idx >= K * N) return;
    int n = idx / K;
    int k = idx - n * K;
    wt[idx] = __float2bfloat16(w[(size_t)k * N + n]);
}

// ---------------- sincos positional embedding ----------------
__global__ void embed_kernel(const float* __restrict__ pos, __hip_bfloat16* __restrict__ outp,
                             int n, int stride, int coloff) {
    int idx = blockIdx.x * blockDim.x + threadIdx.x;
    if (idx >= n * 96) return;
    int nn = idx / 96;
    int rr = idx - nn * 96;
    int d = rr >> 5;
    int k = rr & 31;
    float v = pos[nn * 3 + d];
    float omega = expf(-0.28782313662425575f * (float)k);  // ln(10000)/32
    float a = v * omega;
    __hip_bfloat16* o = outp + (size_t)nn * stride + coloff + d * 64 + k;
    o[0]  = __float2bfloat16(sinf(a));
    o[32] = __float2bfloat16(cosf(a));
}

// ---------------- layer 1: h1 = gelu(x @ w1 + b1), K=16 ----------------
__global__ void lin1_kernel(const float* __restrict__ x, const float* __restrict__ w,
                            const float* __restrict__ b, __hip_bfloat16* __restrict__ h1) {
    int idx = blockIdx.x * blockDim.x + threadIdx.x;
    if (idx >= NMESH * HID) return;
    int m = idx / HID;
    int n = idx - m * HID;
    float acc = b[n];
    const float* xr = x + m * 16;
    #pragma unroll
    for (int k = 0; k < 16; k++) acc = fmaf(xr[k], w[k * HID + n], acc);
    h1[idx] = __float2bfloat16(gelu_f(acc));
}

// ---------------- bf16 MFMA GEMM: C = act(A @ Wt^T + bias) ----------------
// 128x128 tile, BK=32, 4 waves (2x2), 16x16x32 MFMA, double-buffered LDS,
// global_load_lds staging with PRE-SWIZZLED global source (m173/m201 trick):
//   physical LDS slot p (linear in lane order, forced by gload_lds) holds
//   (row = p>>2, kc = (p&3) ^ ((p>>3)&3)).
// -> 4 consecutive lanes still fetch one row's contiguous 64B (coalesced);
// -> fragment reads at kqx = kq ^ ((lr>>1)&3): every 8-lane group hits 8
//    distinct 16B-slots mod 8 = conflict-free ds_read_b128 (verified by
//    enumeration); kqx is lane-constant so no extra addr cost.
template<bool GATHER, bool GELU>
__launch_bounds__(256, 4)
__global__ void mfma_gemm(const __hip_bfloat16* __restrict__ A,
                          const __hip_bfloat16* __restrict__ Wt,
                          const float* __restrict__ bias,
                          __hip_bfloat16* __restrict__ C,
                          int M, int N, int K, int ldc,
                          const int* __restrict__ edges,
                          const __hip_bfloat16* __restrict__ meshf,
                          const __hip_bfloat16* __restrict__ gridf) {
    __shared__ __align__(16) __hip_bfloat16 As[2][4096];
    __shared__ __align__(16) __hip_bfloat16 Bs[2][4096];

    const int t = threadIdx.x;
    const int lane = t & 63;
    const int wave = t >> 6;
    const int wm0 = (wave >> 1) * 64;
    const int wn0 = (wave & 1) * 64;

    int bx, by;
    xcd_swizzle(bx, by);
    const int row0 = by * 128;
    const int col0 = bx * 128;

    // staging: thread t covers physical slots t (rows 0..63) and t+256 (rows 64..127)
    const int rS0 = t >> 2;
    const int rS1 = rS0 + 64;
    const int kcS = (t & 3) ^ ((t >> 3) & 3);   // logical k-chunk (same both issues)

    const __hip_bfloat16 *aP0, *aP1, *aQ0 = nullptr, *aQ1 = nullptr;
    if constexpr (GATHER) {
        int e0 = min(row0 + rS0, M - 1);
        int e1 = min(row0 + rS1, M - 1);
        aP0 = meshf + (size_t)edges[2 * e0 + 1] * 576;
        aQ0 = gridf + (size_t)edges[2 * e0 + 0] * 192;
        aP1 = meshf + (size_t)edges[2 * e1 + 1] * 576;
        aQ1 = gridf + (size_t)edges[2 * e1 + 0] * 192;
    } else {
        aP0 = A + (size_t)min(row0 + rS0, M - 1) * K;
        aP1 = A + (size_t)min(row0 + rS1, M - 1) * K;
    }
    const __hip_bfloat16* bP0 = Wt + (size_t)(col0 + rS0) * K;
    const __hip_bfloat16* bP1 = Wt + (size_t)(col0 + rS1) * K;

    // wave-uniform LDS dest byte bases (HW adds lane*16)
    const int off0 = (wave * 64) * 16;
    const int off1 = (256 + wave * 64) * 16;

    f32x4 acc[4][4] = {};

    const int kq = lane >> 4;
    const int lr = lane & 15;
    const int kqx = kq ^ ((lr >> 1) & 3);   // swizzled k-chunk for fragment reads
    // fragment read element base: (rowbase+lr)*32 + kqx*8; fragment i at +i*512
    const int rdA = (wm0 + lr) * 32 + kqx * 8;
    const int rdB = (wn0 + lr) * 32 + kqx * 8;

    const int nsteps = K >> 5;

    auto stage = [&](int ks, int buf) {
        int k = ks * 32 + kcS * 8;
        const __hip_bfloat16 *sa0, *sa1;
        if constexpr (GATHER) {
            sa0 = (k < 576) ? (aP0 + k) : (aQ0 + (k - 576));
            sa1 = (k < 576) ? (aP1 + k) : (aQ1 + (k - 576));
        } else {
            sa0 = aP0 + k;
            sa1 = aP1 + k;
        }
        load_lds16(sa0, (char*)As[buf] + off0);
        load_lds16(sa1, (char*)As[buf] + off1);
        load_lds16(bP0 + k, (char*)Bs[buf] + off0);
        load_lds16(bP1 + k, (char*)Bs[buf] + off1);
    };

    // prologue: fill buffer 0
    stage(0, 0);
    __syncthreads();

    int cur = 0;
    for (int ks = 0; ks < nsteps; ks++) {
        if (ks + 1 < nsteps) stage(ks + 1, cur ^ 1);  // issue next-tile loads first

        bfrag aF[4], bF[4];
        #pragma unroll
        for (int i = 0; i < 4; i++) {
            aF[i] = *reinterpret_cast<const bfrag*>(&As[cur][rdA + i * 512]);
            bF[i] = *reinterpret_cast<const bfrag*>(&Bs[cur][rdB + i * 512]);
        }
        #pragma unroll
        for (int i = 0; i < 4; i++) {
            #pragma unroll
            for (int j = 0; j < 4; j++) {
                acc[i][j] = __builtin_amdgcn_mfma_f32_16x16x32_bf16(aF[i], bF[j], acc[i][j], 0, 0, 0);
            }
        }
        __syncthreads();  // drains vmcnt: next buffer ready; cur's ds_reads done
        cur ^= 1;
    }

    // C/D layout: col = lane&15, row = (lane>>4)*4 + reg
    #pragma unroll
    for (int i = 0; i < 4; i++) {
        #pragma unroll
        for (int j = 0; j < 4; j++) {
            #pragma unroll
            for (int r = 0; r < 4; r++) {
                int row = row0 + wm0 + i * 16 + kq * 4 + r;
                int col = col0 + wn0 + j * 16 + lr;
                if (row < M) {
                    float v = acc[i][j][r] + bias[col];
                    if constexpr (GELU) v = gelu_f(v);
                    C[(size_t)row * ldc + col] = __float2bfloat16(v);
                }
            }
        }
    }
}

// ---------------- per-chunk segment partial sums (sorted grid_idx, no atomics) ----------------
__global__ void seg_partial(const int* __restrict__ edges, int e0, int e1,
                            const __hip_bfloat16* __restrict__ m3c, float* __restrict__ out) {
    int g = blockIdx.x;
    int l = e0, r = e1;
    while (l < r) { int mid = (l + r) >> 1; if (edges[2 * mid] < g) l = mid + 1; else r = mid; }
    int lo = l;
    r = e1;
    while (l < r) { int mid = (l + r) >> 1; if (edges[2 * mid] <= g) l = mid + 1; else r = mid; }
    int hi = l;
    if (lo >= hi) return;

    int c = threadIdx.x;
    float s0 = 0.f, s1 = 0.f, s2 = 0.f;
    for (int e = lo; e < hi; e++) {
        const __hip_bfloat16* rp = m3c + (size_t)(e - e0) * HID;
        s0 += __bfloat162float(rp[c]);
        s1 += __bfloat162float(rp[c + 128]);
        s2 += __bfloat162float(rp[c + 256]);
    }
    float* orow = out + (size_t)g * HID;
    orow[c] += s0;
    orow[c + 128] += s1;
    orow[c + 256] += s2;
}

// ---------------- final divide by segment count ----------------
__global__ void seg_div(const int* __restrict__ edges, float* __restrict__ out) {
    int g = blockIdx.x;
    int l = 0, r = NEDGE;
    while (l < r) { int mid = (l + r) >> 1; if (edges[2 * mid] < g) l = mid + 1; else r = mid; }
    int lo = l;
    r = NEDGE;
    while (l < r) { int mid = (l + r) >> 1; if (edges[2 * mid] <= g) l = mid + 1; else r = mid; }
    int cnt = l - lo;
    float inv = 1.0f / (float)max(cnt, 1);
    int c = threadIdx.x;
    float* orow = out + (size_t)g * HID;
    orow[c] *= inv;
    orow[c + 128] *= inv;
    orow[c + 256] *= inv;
}

extern "C" void kernel_launch(void* const* d_in, const int* in_sizes, int n_in,
                              void* d_out, int out_size, void* d_ws, size_t ws_size,
                              hipStream_t stream) {
    const float* x        = (const float*)d_in[0];
    const float* mesh_pos = (const float*)d_in[1];
    const float* grid_pos = (const float*)d_in[2];
    const int*   edges    = (const int*)d_in[3];
    const float* w1  = (const float*)d_in[4];
    const float* b1  = (const float*)d_in[5];
    const float* w2  = (const float*)d_in[6];
    const float* b2  = (const float*)d_in[7];
    const float* w3  = (const float*)d_in[8];
    const float* b3  = (const float*)d_in[9];
    const float* wm1 = (const float*)d_in[10];
    const float* bm1 = (const float*)d_in[11];
    const float* wm2 = (const float*)d_in[12];
    const float* bm2 = (const float*)d_in[13];
    const float* wm3 = (const float*)d_in[14];
    const float* bm3 = (const float*)d_in[15];
    float* out = (float*)d_out;

    // ---- workspace layout, ~174 MB total ----
    char* p = (char*)d_ws;
    auto alloc = [&](size_t b) { char* r = p; p += (b + 255) & ~(size_t)255; return r; };
    __hip_bfloat16* wt2   = (__hip_bfloat16*)alloc((size_t)384 * 384 * 2);
    __hip_bfloat16* wt3   = (__hip_bfloat16*)alloc((size_t)384 * 384 * 2);
    __hip_bfloat16* wtm1  = (__hip_bfloat16*)alloc((size_t)768 * 768 * 2);
    __hip_bfloat16* wtm2  = (__hip_bfloat16*)alloc((size_t)768 * 768 * 2);
    __hip_bfloat16* wtm3  = (__hip_bfloat16*)alloc((size_t)384 * 768 * 2);
    __hip_bfloat16* gridf = (__hip_bfloat16*)alloc((size_t)GRIDN * 192 * 2);
    __hip_bfloat16* meshf = (__hip_bfloat16*)alloc((size_t)NMESH * 576 * 2);
    char* U1 = alloc((size_t)CHUNK * 768 * 2);
    char* U2 = alloc((size_t)CHUNK * 768 * 2);
    __hip_bfloat16* h1  = (__hip_bfloat16*)U1;
    __hip_bfloat16* h2  = (__hip_bfloat16*)U2;
    __hip_bfloat16* m1c = (__hip_bfloat16*)U1;
    __hip_bfloat16* m2c = (__hip_bfloat16*)U2;
    __hip_bfloat16* m3c = (__hip_bfloat16*)U1;  // m1c dead once m2c computed

    hipMemsetAsync(out, 0, (size_t)GRIDN * HID * 4, stream);

    transpose_to_bf16<<<(384 * 384 + 255) / 256, 256, 0, stream>>>(w2, wt2, 384, 384);
    transpose_to_bf16<<<(384 * 384 + 255) / 256, 256, 0, stream>>>(w3, wt3, 384, 384);
    transpose_to_bf16<<<(768 * 768 + 255) / 256, 256, 0, stream>>>(wm1, wtm1, 768, 768);
    transpose_to_bf16<<<(768 * 768 + 255) / 256, 256, 0, stream>>>(wm2, wtm2, 768, 768);
    transpose_to_bf16<<<(768 * 384 + 255) / 256, 256, 0, stream>>>(wm3, wtm3, 768, 384);

    embed_kernel<<<(NMESH * 96 + 255) / 256, 256, 0, stream>>>(mesh_pos, meshf, NMESH, 576, 384);
    embed_kernel<<<(GRIDN * 96 + 255) / 256, 256, 0, stream>>>(grid_pos, gridf, GRIDN, 192, 0);

    lin1_kernel<<<(NMESH * HID + 255) / 256, 256, 0, stream>>>(x, w1, b1, h1);

    // h2 = gelu(h1 @ w2 + b2)
    mfma_gemm<false, true><<<dim3(3, 391), 256, 0, stream>>>(
        h1, wt2, b2, h2, NMESH, 384, 384, 384, nullptr, nullptr, nullptr);
    // mesh_feat[:, :384] = h2 @ w3 + b3
    mfma_gemm<false, false><<<dim3(3, 391), 256, 0, stream>>>(
        h2, wt3, b3, meshf, NMESH, 384, 384, 576, nullptr, nullptr, nullptr);

    for (int c = 0; c < NCHUNK; c++) {
        int e0 = c * CHUNK;
        // m1c = gelu(gather(edges[e0:e0+CHUNK]) @ wm1 + bm1)
        mfma_gemm<true, true><<<dim3(6, CHUNK / 128), 256, 0, stream>>>(
            nullptr, wtm1, bm1, m1c, CHUNK, 768, 768, 768, edges + 2 * e0, meshf, gridf);
        // m2c = gelu(m1c @ wm2 + bm2)
        mfma_gemm<false, true><<<dim3(6, CHUNK / 128), 256, 0, stream>>>(
            m1c, wtm2, bm2, m2c, CHUNK, 768, 768, 768, nullptr, nullptr, nullptr);
        // m3c = m2c @ wm3 + bm3   (overwrites m1c region — m1c dead)
        mfma_gemm<false, false><<<dim3(3, CHUNK / 128), 256, 0, stream>>>(
            m2c, wtm3, bm3, m3c, CHUNK, 384, 768, 384, nullptr, nullptr, nullptr);
        // accumulate segment sums for this chunk
        seg_partial<<<GRIDN, 128, 0, stream>>>(edges, e0, e0 + CHUNK, m3c, out);
    }

    seg_div<<<GRIDN, 128, 0, stream>>>(edges, out);
}